// Round 1
// baseline (151.248 us; speedup 1.0000x reference)
//
#include <hip/hip_runtime.h>

// NBCModel: non-backtracking closed-walk signature + MLP.
// B[i,j] = (dst_j == src_i) && (src_j != dst_i)  -- edge-level non-backtracking step.
// sig[g,k] = sum_{i in graph g} diag(B^{k+1})_i  = # closed NB walks of length k+1 from edge i.
// out[g] = relu(sig[g] @ W1 + b1) @ W2 + b2.
//
// B has ~E^2/N ~= 1024 nonzeros (avg out-degree 0.5), so we enumerate walks by
// DFS instead of 8 dense 2048^3 matmuls. Everything fits in one block's LDS.

constexpr int E_EDGES  = 2048;
constexpr int L_WALK   = 8;
constexpr int G_GRAPHS = 128;
constexpr int HID      = 128;
constexpr int N_NODES  = 4096;
constexpr int BLOCK    = 256;

__launch_bounds__(BLOCK, 1)
__global__ void nbc_all(const int* __restrict__ edge_index,
                        const int* __restrict__ edge_graph,
                        const float* __restrict__ W1,
                        const float* __restrict__ b1,
                        const float* __restrict__ W2,
                        const float* __restrict__ b2,
                        float* __restrict__ out)
{
    __shared__ int s_cnt[N_NODES];          // bucket counts, reused as fill cursor
    __shared__ int s_off[N_NODES + 1];      // CSR offsets (bucket by dst node)
    __shared__ int s_bucket[E_EDGES];       // edge ids grouped by dst node
    __shared__ int s_sig[G_GRAPHS * L_WALK];// integer walk counts per (graph, length)
    __shared__ int s_wave[4];               // per-wave scan partials

    const int t    = threadIdx.x;
    const int lane = t & 63;
    const int wave = t >> 6;
    const int* src = edge_index;            // edge_index[0, :]
    const int* dst = edge_index + E_EDGES;  // edge_index[1, :]

    // ---- init ----
    for (int n = t; n < N_NODES; n += BLOCK) s_cnt[n] = 0;
    for (int n = t; n < G_GRAPHS * L_WALK; n += BLOCK) s_sig[n] = 0;
    __syncthreads();

    // ---- count edges per dst node ----
    for (int e = t; e < E_EDGES; e += BLOCK) atomicAdd(&s_cnt[dst[e]], 1);
    __syncthreads();

    // ---- exclusive scan of 4096 counts (16 per thread + wave shuffle scan) ----
    const int base = t * (N_NODES / BLOCK); // 16 elems/thread
    int loc[16];
    int run = 0;
    #pragma unroll
    for (int j = 0; j < 16; ++j) { loc[j] = run; run += s_cnt[base + j]; }
    int incl = run;
    #pragma unroll
    for (int off = 1; off < 64; off <<= 1) {
        int v = __shfl_up(incl, off);
        if (lane >= off) incl += v;
    }
    if (lane == 63) s_wave[wave] = incl;
    __syncthreads();
    int wbase = 0;
    for (int w = 0; w < wave; ++w) wbase += s_wave[w];
    const int start = wbase + incl - run;   // exclusive prefix for this thread's chunk
    #pragma unroll
    for (int j = 0; j < 16; ++j) s_off[base + j] = start + loc[j];
    if (t == 0) s_off[N_NODES] = E_EDGES;
    __syncthreads();

    // ---- fill buckets (cursor = copy of offsets) ----
    for (int n = t; n < N_NODES; n += BLOCK) s_cnt[n] = s_off[n];
    __syncthreads();
    for (int e = t; e < E_EDGES; e += BLOCK) {
        int pos = atomicAdd(&s_cnt[dst[e]], 1);
        s_bucket[pos] = e;
    }
    __syncthreads();

    // ---- DFS per start edge: count closed NB walks of length 1..8 ----
    for (int i = t; i < E_EDGES; i += BLOCK) {
        int cnt[L_WALK];
        #pragma unroll
        for (int k = 0; k < L_WALK; ++k) cnt[k] = 0;

        // state at depth d: current edge c_d (c_0 = i); p/pe iterate successors
        // (edges b with dst_b == src_{c_d}); dc = dst of c_d for the NB check.
        int p[L_WALK], pe[L_WALK], dc[L_WALK];
        int depth = 0;
        {
            int sc = src[i];
            p[0]  = s_off[sc];
            pe[0] = s_off[sc + 1];
            dc[0] = dst[i];
        }
        while (true) {
            if (p[depth] < pe[depth]) {
                int b  = s_bucket[p[depth]++]; // dst_b == src of current edge
                int sb = src[b];
                if (sb != dc[depth]) {         // non-backtracking
                    if (b == i) cnt[depth]++;  // closed walk, length depth+1
                    if (depth + 1 < L_WALK) {
                        ++depth;
                        dc[depth] = dst[b];
                        p[depth]  = s_off[sb];
                        pe[depth] = s_off[sb + 1];
                    }
                }
            } else {
                if (depth == 0) break;
                --depth;
            }
        }

        int g = edge_graph[i];
        #pragma unroll
        for (int k = 0; k < L_WALK; ++k)
            if (cnt[k]) atomicAdd(&s_sig[g * L_WALK + k], cnt[k]);
    }
    __syncthreads();

    // ---- MLP: out[g] = relu(sig @ W1 + b1) @ W2 + b2 ----
    if (t < G_GRAPHS) {
        float sig[L_WALK];
        #pragma unroll
        for (int k = 0; k < L_WALK; ++k) sig[k] = (float)s_sig[t * L_WALK + k];
        float o = b2[0];
        for (int j = 0; j < HID; ++j) {
            float a = b1[j];
            #pragma unroll
            for (int k = 0; k < L_WALK; ++k) a += sig[k] * W1[k * HID + j];
            o += fmaxf(a, 0.0f) * W2[j];
        }
        out[t] = o;
    }
}

extern "C" void kernel_launch(void* const* d_in, const int* in_sizes, int n_in,
                              void* d_out, int out_size, void* d_ws, size_t ws_size,
                              hipStream_t stream) {
    const int*   edge_index = (const int*)d_in[0];
    const int*   edge_graph = (const int*)d_in[1];
    const float* W1 = (const float*)d_in[2];
    const float* b1 = (const float*)d_in[3];
    const float* W2 = (const float*)d_in[4];
    const float* b2 = (const float*)d_in[5];
    float* out = (float*)d_out;

    nbc_all<<<1, BLOCK, 0, stream>>>(edge_index, edge_graph, W1, b1, W2, b2, out);
}

// Round 2
// 90.511 us; speedup vs baseline: 1.6710x; 1.6710x over previous
//
#include <hip/hip_runtime.h>

// NBCModel: non-backtracking closed-walk signature + MLP.
// B[i,j] = (dst_j == src_i) && (src_j != dst_i).  sig[g,k] = sum over edges i in
// graph g of diag(B^{k+1})_i.  out[g] = relu(sig @ W1 + b1) @ W2 + b2.
//
// Round-1 DFS was latency-bound (VALUBusy 0.08%): serial per-thread DFS with
// dependent ds_read chains + wave divergence. Round 2: level-synchronous BFS
// over (start,current) pairs — each level is a flat parallel loop, load-balanced
// across 256 threads, walk counts stay exact integers.

constexpr int E_EDGES  = 2048;
constexpr int L_WALK   = 8;
constexpr int G_GRAPHS = 128;
constexpr int HID      = 128;
constexpr int N_NODES  = 4096;
constexpr int BLOCK    = 256;
constexpr int CAP      = 4736;   // frontier capacity (expected max level ~1024)

__launch_bounds__(BLOCK, 1)
__global__ void nbc_all(const int* __restrict__ edge_index,
                        const int* __restrict__ edge_graph,
                        const float* __restrict__ W1,
                        const float* __restrict__ b1,
                        const float* __restrict__ W2,
                        const float* __restrict__ b2,
                        float* __restrict__ out)
{
    __shared__ unsigned short s_off[N_NODES + 2]; // CSR offsets (bucket by dst node)
    __shared__ unsigned short s_bucket[E_EDGES];  // edge ids grouped by dst node
    __shared__ unsigned s_srcdst[E_EDGES];        // src | dst<<12
    __shared__ unsigned char s_graph[E_EDGES];    // graph id per edge
    __shared__ int s_sig[G_GRAPHS * L_WALK];      // integer walk counts
    __shared__ unsigned s_bufA[CAP];              // frontier ping (aliased as s_cnt)
    __shared__ unsigned s_bufB[CAP];              // frontier pong
    __shared__ int s_nn[L_WALK];                  // frontier size per level
    __shared__ int s_wave[4];                     // scan partials

    int* s_cnt = (int*)s_bufA;                    // alias: counts/cursors (4096 ints)

    const int t    = threadIdx.x;
    const int lane = t & 63;
    const int wave = t >> 6;
    const int* src = edge_index;
    const int* dst = edge_index + E_EDGES;

    // ---- init + load edges into LDS ----
    for (int n = t; n < N_NODES; n += BLOCK) s_cnt[n] = 0;
    for (int n = t; n < G_GRAPHS * L_WALK; n += BLOCK) s_sig[n] = 0;
    if (t < L_WALK) s_nn[t] = 0;
    for (int e = t; e < E_EDGES; e += BLOCK) {
        int se = src[e], de = dst[e];
        s_srcdst[e] = (unsigned)se | ((unsigned)de << 12);
        s_graph[e]  = (unsigned char)edge_graph[e];
    }
    __syncthreads();

    // ---- count edges per dst node ----
    for (int e = t; e < E_EDGES; e += BLOCK)
        atomicAdd(&s_cnt[s_srcdst[e] >> 12], 1);
    __syncthreads();

    // ---- exclusive scan of 4096 counts → u16 offsets ----
    const int base = t * (N_NODES / BLOCK); // 16 elems/thread
    int loc[16];
    int run = 0;
    #pragma unroll
    for (int j = 0; j < 16; ++j) { loc[j] = run; run += s_cnt[base + j]; }
    int incl = run;
    #pragma unroll
    for (int off = 1; off < 64; off <<= 1) {
        int v = __shfl_up(incl, off);
        if (lane >= off) incl += v;
    }
    if (lane == 63) s_wave[wave] = incl;
    __syncthreads();
    int wbase = 0;
    for (int w = 0; w < wave; ++w) wbase += s_wave[w];
    const int start = wbase + incl - run;
    __syncthreads();                 // counts consumed; s_cnt (bufA) to be reused
    #pragma unroll
    for (int j = 0; j < 16; ++j) s_off[base + j] = (unsigned short)(start + loc[j]);
    if (t == 0) s_off[N_NODES] = E_EDGES;
    __syncthreads();

    // ---- fill buckets (cursor = copy of offsets, in s_cnt alias) ----
    for (int n = t; n < N_NODES; n += BLOCK) s_cnt[n] = s_off[n];
    __syncthreads();
    for (int e = t; e < E_EDGES; e += BLOCK) {
        int pos = atomicAdd(&s_cnt[s_srcdst[e] >> 12], 1);
        s_bucket[pos] = (unsigned short)e;
    }
    __syncthreads();                 // bucket done; bufA free for frontier

    // ---- level 0: expand each start edge, push walks of length 1 ----
    for (int i = t; i < E_EDGES; i += BLOCK) {
        unsigned sd = s_srcdst[i];
        int sc  = sd & 0xFFF;
        int dcc = sd >> 12;
        int lo = s_off[sc], hi = s_off[sc + 1];
        for (int p = lo; p < hi; ++p) {
            int b = s_bucket[p];
            unsigned sdb = s_srcdst[b];
            if ((int)(sdb & 0xFFF) != dcc) {       // non-backtracking
                if (b == i) atomicAdd(&s_sig[(int)s_graph[i] * L_WALK + 0], 1);
                int pos = atomicAdd(&s_nn[1], 1);
                if (pos < CAP) s_bufA[pos] = (unsigned)i | ((unsigned)b << 11);
            }
        }
    }

    // ---- levels 1..7: expand frontier, count closed walks ----
    unsigned* cur = s_bufA;
    unsigned* nxt = s_bufB;
    for (int d = 1; d < L_WALK; ++d) {
        __syncthreads();             // frontier for level d complete
        int n_cur = s_nn[d];
        if (n_cur > CAP) n_cur = CAP;
        for (int idx = t; idx < n_cur; idx += BLOCK) {
            unsigned pr = cur[idx];
            int s = pr & 0x7FF;
            int c = pr >> 11;
            unsigned sd = s_srcdst[c];
            int sc  = sd & 0xFFF;
            int dcc = sd >> 12;
            int lo = s_off[sc], hi = s_off[sc + 1];
            for (int p = lo; p < hi; ++p) {
                int b = s_bucket[p];
                unsigned sdb = s_srcdst[b];
                if ((int)(sdb & 0xFFF) != dcc) {
                    if (b == s) atomicAdd(&s_sig[(int)s_graph[s] * L_WALK + d], 1);
                    if (d < L_WALK - 1) {
                        int pos = atomicAdd(&s_nn[d + 1], 1);
                        if (pos < CAP) nxt[pos] = (unsigned)s | ((unsigned)b << 11);
                    }
                }
            }
        }
        unsigned* tmp = cur; cur = nxt; nxt = tmp;
    }
    __syncthreads();                 // s_sig final

    // ---- MLP: out[g] = relu(sig @ W1 + b1) @ W2 + b2 ----
    if (t < G_GRAPHS) {
        float sig[L_WALK];
        #pragma unroll
        for (int k = 0; k < L_WALK; ++k) sig[k] = (float)s_sig[t * L_WALK + k];
        float o = b2[0];
        for (int j = 0; j < HID; ++j) {
            float a = b1[j];
            #pragma unroll
            for (int k = 0; k < L_WALK; ++k) a += sig[k] * W1[k * HID + j];
            o += fmaxf(a, 0.0f) * W2[j];
        }
        out[t] = o;
    }
}

extern "C" void kernel_launch(void* const* d_in, const int* in_sizes, int n_in,
                              void* d_out, int out_size, void* d_ws, size_t ws_size,
                              hipStream_t stream) {
    const int*   edge_index = (const int*)d_in[0];
    const int*   edge_graph = (const int*)d_in[1];
    const float* W1 = (const float*)d_in[2];
    const float* b1 = (const float*)d_in[3];
    const float* W2 = (const float*)d_in[4];
    const float* b2 = (const float*)d_in[5];
    float* out = (float*)d_out;

    nbc_all<<<1, BLOCK, 0, stream>>>(edge_index, edge_graph, W1, b1, W2, b2, out);
}